// Round 3
// baseline (772.859 us; speedup 1.0000x reference)
//
#include <hip/hip_runtime.h>

typedef _Float16 f16;
typedef _Float16 f16x4 __attribute__((ext_vector_type(4)));
typedef _Float16 f16x8 __attribute__((ext_vector_type(8)));
typedef float f32x4 __attribute__((ext_vector_type(4)));

#define TPB 576            // 9 waves
#define NWIN 16            // windows per block
#define XS 200             // Xh row stride (halves): 400B = 25x16B (odd) -> conflict-free b128
#define WSS 200            // Wh row stride
#define QS 40              // Qh/Kh/AOh/Wph row stride: 80B = 5x16B (odd)
#define VS 280             // Vt2 row stride: 560B = 35x16B (odd)
#define PS 40              // P scratch row stride (cols 16..31 stay zero for K=32 fallback)

__global__ __launch_bounds__(TPB) void lsa_mfma2(
    const float* __restrict__ x, const float* __restrict__ Wqkv,
    const float* __restrict__ Wproj, const float* __restrict__ bproj,
    float* __restrict__ out)
{
    // LDS (bytes): Xh 57600 | Wh 38400 (Wph aliases head of it) | Qh 12160 |
    // Kh 12160 | Vt2 17920 | AOh 11520 | Ps 11520  => 161280 B
    __shared__ f16 Xh[144 * XS];
    __shared__ f16 Wh[96 * WSS];
    __shared__ f16 Qh[152 * QS];
    __shared__ f16 Kh[152 * QS];
    __shared__ f16 Vt2[32 * VS];
    __shared__ f16 AOh[144 * QS];
    __shared__ f16 Ps[9 * 16 * PS];   // per-wave P-transpose scratch

    const int tid  = threadIdx.x;
    const int lane = tid & 63;
    const int w    = tid >> 6;      // wave 0..8
    const int mi   = w / 3;         // M-group 0..2
    const int ni   = w % 3;         // N-group 0..2
    const int l15  = lane & 15;
    const int lg   = lane >> 4;     // 0..3

    // ---- geometry: 16 windows per block ----
    const int  bb    = blockIdx.x / 768;
    const int  gbase = (blockIdx.x % 768) * NWIN;
    const long rb0   = (long)bb * 110592 + (long)(gbase / 96) * 864 + (long)(gbase % 96) * 3;

    // ---- phase 0: X -> LDS fp16; zero Vt2 and Ps ----
    for (int idx = tid; idx < 144 * 48; idx += TPB) {   // 12 exact iters
        int t = idx / 48, c4 = idx % 48;
        int wi = t / 9, q = t - 9 * wi;
        long grow = rb0 + wi * 3 + (q / 3) * 288 + (q % 3);
        float4 xv = ((const float4*)x)[grow * 48 + c4];
        union { f16 h[4]; ushort4 u; } tmp;
        tmp.h[0] = (f16)xv.x; tmp.h[1] = (f16)xv.y; tmp.h[2] = (f16)xv.z; tmp.h[3] = (f16)xv.w;
        *(ushort4*)&Xh[t * XS + c4 * 4] = tmp.u;
    }
    {
        int4 z = {0, 0, 0, 0};
        for (int i2 = tid; i2 < (32 * VS * 2) / 16;     i2 += TPB) ((int4*)Vt2)[i2] = z;
        for (int i2 = tid; i2 < (9 * 16 * PS * 2) / 16; i2 += TPB) ((int4*)Ps)[i2]  = z;
    }

    // ---- weight prefetch registers (T14 async-stage): head 0 ----
    const float4* Wq4 = (const float4*)Wqkv;
    const float4* Wp4 = (const float4*)Wproj;
    float4 wq[8];            // Wqkv head slice: 96 rows x 48 f4 = 4608 = 8*576
    float4 wpc[3], wpn[3];   // Wproj head slice: 192 rows x 8 f4 = 1536 = 3*512
    #pragma unroll
    for (int i = 0; i < 8; ++i) {
        int l = i * TPB + tid;
        int r = l / 48, c4 = l % 48;
        wq[i] = Wq4[((r >> 5) * 192 + (r & 31)) * 48 + c4];           // head 0
    }
    if (tid < 512) {
        #pragma unroll
        for (int i = 0; i < 3; ++i) {
            int l = i * 512 + tid;
            int r = l / 8, c4 = l % 8;
            wpc[i] = Wp4[r * 48 + c4];                                 // head 0
        }
    }

    f32x4 pacc[3][4];
    #pragma unroll
    for (int a = 0; a < 3; ++a)
        #pragma unroll
        for (int bq = 0; bq < 4; ++bq)
            pacc[a][bq] = (f32x4){0.f, 0.f, 0.f, 0.f};

    __syncthreads();

    for (int h = 0; h < 6; ++h) {
        // ---- write Wqkv head slice from prefetched regs ----
        #pragma unroll
        for (int i = 0; i < 8; ++i) {
            int l = i * TPB + tid;
            int r = l / 48, c4 = l % 48;
            union { f16 h4[4]; ushort4 u; } t;
            t.h4[0] = (f16)wq[i].x; t.h4[1] = (f16)wq[i].y;
            t.h4[2] = (f16)wq[i].z; t.h4[3] = (f16)wq[i].w;
            *(ushort4*)&Wh[r * WSS + c4 * 4] = t.u;
        }
        __syncthreads();   // A: Wh ready

        // ---- prefetch next head's weights into regs (latency hidden by compute) ----
        if (h < 5) {
            #pragma unroll
            for (int i = 0; i < 8; ++i) {
                int l = i * TPB + tid;
                int r = l / 48, c4 = l % 48;
                wq[i] = Wq4[((r >> 5) * 192 + (h + 1) * 32 + (r & 31)) * 48 + c4];
            }
            if (tid < 512) {
                #pragma unroll
                for (int i = 0; i < 3; ++i) {
                    int l = i * 512 + tid;
                    int r = l / 8, c4 = l % 8;
                    wpn[i] = Wp4[r * 48 + (h + 1) * 8 + c4];
                }
            }
        }

        // ---- QKV GEMM: X(144x192) @ Wh(96x192)^T ----
        f32x4 qacc[3][2];
        #pragma unroll
        for (int a = 0; a < 3; ++a)
            #pragma unroll
            for (int c = 0; c < 2; ++c)
                qacc[a][c] = (f32x4){0.f, 0.f, 0.f, 0.f};
        #pragma unroll
        for (int kk = 0; kk < 6; ++kk) {
            f16x8 af[3], bf[2];
            #pragma unroll
            for (int a = 0; a < 3; ++a)
                af[a] = *(const f16x8*)&Xh[(16 * (3 * mi + a) + l15) * XS + kk * 32 + lg * 8];
            #pragma unroll
            for (int c = 0; c < 2; ++c)
                bf[c] = *(const f16x8*)&Wh[(16 * (2 * ni + c) + l15) * WSS + kk * 32 + lg * 8];
            #pragma unroll
            for (int a = 0; a < 3; ++a)
                #pragma unroll
                for (int c = 0; c < 2; ++c)
                    qacc[a][c] = __builtin_amdgcn_mfma_f32_16x16x32_f16(af[a], bf[c], qacc[a][c], 0, 0, 0);
        }
        // scatter D-frags: col = l15 (channel), row = lg*4+r (token)
        #pragma unroll
        for (int a = 0; a < 3; ++a) {
            const int trow = 16 * (3 * mi + a) + lg * 4;
            #pragma unroll
            for (int c = 0; c < 2; ++c) {
                const int nt = 2 * ni + c;      // 0..5, wave-uniform
                if (nt < 2) {                   // Q
                    const int d = nt * 16 + l15;
                    #pragma unroll
                    for (int r = 0; r < 4; ++r)
                        Qh[(trow + r) * QS + d] = (f16)qacc[a][c][r];
                } else if (nt < 4) {            // K
                    const int d = (nt - 2) * 16 + l15;
                    #pragma unroll
                    for (int r = 0; r < 4; ++r)
                        Kh[(trow + r) * QS + d] = (f16)qacc[a][c][r];
                } else {                        // V -> [d][window-slot] transpose
                    const int d = (nt - 4) * 16 + l15;
                    #pragma unroll
                    for (int r = 0; r < 4; ++r) {
                        int t = trow + r;
                        int wi = t / 9, qq = t - 9 * wi;
                        Vt2[d * VS + 16 * wi + qq] = (f16)qacc[a][c][r];
                    }
                }
            }
        }
        __syncthreads();   // B: Q/K/V ready; Wh B-reads done

        // ---- write Wproj head slice (aliases head of Wh; read after barrier C) ----
        if (tid < 512) {
            #pragma unroll
            for (int i = 0; i < 3; ++i) {
                int l = i * 512 + tid;
                int r = l / 8, c4 = l % 8;
                union { f16 h4[4]; ushort4 u; } t;
                t.h4[0] = (f16)wpc[i].x; t.h4[1] = (f16)wpc[i].y;
                t.h4[2] = (f16)wpc[i].z; t.h4[3] = (f16)wpc[i].w;
                *(ushort4*)&Wh[r * QS + c4 * 4] = t.u;
            }
        }

        // ---- scores + softmax + in-wave P transpose + PV (no block barrier inside) ----
        f16* myPs = &Ps[w * 16 * PS];
        for (int wi = w; wi < NWIN; wi += 9) {
            f16x8 aq = *(const f16x8*)&Qh[(9 * wi + l15) * QS + lg * 8];
            f16x8 bk = *(const f16x8*)&Kh[(9 * wi + l15) * QS + lg * 8];
            f32x4 s = (f32x4){0.f, 0.f, 0.f, 0.f};
            s = __builtin_amdgcn_mfma_f32_16x16x32_f16(aq, bk, s, 0, 0, 0);
            // D: col=l15=key, row=lg*4+r=q (window-local). Softmax over keys (l15).
            #pragma unroll
            for (int r = 0; r < 4; ++r) {
                float lgt = (l15 < 9) ? s[r] * 0.17677669529663687f : -1e30f;
                float mx = lgt;
                mx = fmaxf(mx, __shfl_xor(mx, 1));
                mx = fmaxf(mx, __shfl_xor(mx, 2));
                mx = fmaxf(mx, __shfl_xor(mx, 4));
                mx = fmaxf(mx, __shfl_xor(mx, 8));
                float e = __expf(lgt - mx);
                float sm = e;
                sm += __shfl_xor(sm, 1);
                sm += __shfl_xor(sm, 2);
                sm += __shfl_xor(sm, 4);
                sm += __shfl_xor(sm, 8);
                myPs[(lg * 4 + r) * PS + l15] = (f16)(e / sm);   // P[q][k], in-wave
            }
            // PV: O(16x32) = P(16x16) @ V(16x32); A=P[q][k], B=V[d][k-slot]
#if __has_builtin(__builtin_amdgcn_mfma_f32_16x16x16f16)
            f16x4 ap  = *(const f16x4*)&myPs[l15 * PS + lg * 4];
            f16x4 bv0 = *(const f16x4*)&Vt2[l15 * VS + 16 * wi + lg * 4];
            f16x4 bv1 = *(const f16x4*)&Vt2[(16 + l15) * VS + 16 * wi + lg * 4];
            f32x4 o0 = (f32x4){0.f, 0.f, 0.f, 0.f};
            f32x4 o1 = (f32x4){0.f, 0.f, 0.f, 0.f};
            o0 = __builtin_amdgcn_mfma_f32_16x16x16f16(ap, bv0, o0, 0, 0, 0);
            o1 = __builtin_amdgcn_mfma_f32_16x16x16f16(ap, bv1, o1, 0, 0, 0);
#else
            // K=32 fallback: Ps cols 16..31 and Vt2 slots 9..15 are zero
            f16x8 ap  = *(const f16x8*)&myPs[l15 * PS + lg * 8];
            f16x8 bv0 = *(const f16x8*)&Vt2[l15 * VS + 16 * wi + lg * 8];
            f16x8 bv1 = *(const f16x8*)&Vt2[(16 + l15) * VS + 16 * wi + lg * 8];
            f32x4 o0 = (f32x4){0.f, 0.f, 0.f, 0.f};
            f32x4 o1 = (f32x4){0.f, 0.f, 0.f, 0.f};
            o0 = __builtin_amdgcn_mfma_f32_16x16x32_f16(ap, bv0, o0, 0, 0, 0);
            o1 = __builtin_amdgcn_mfma_f32_16x16x32_f16(ap, bv1, o1, 0, 0, 0);
#endif
            // AO scatter: D col=l15=d, row=lg*4+r=q; keep q<9
            #pragma unroll
            for (int r = 0; r < 4; ++r) {
                int q = lg * 4 + r;
                if (q < 9) {
                    AOh[(9 * wi + q) * QS + l15]      = (f16)o0[r];
                    AOh[(9 * wi + q) * QS + 16 + l15] = (f16)o1[r];
                }
            }
        }
        __syncthreads();   // C: AOh + Wph ready

        // ---- proj partial: out += AO_h(144x32) @ Wproj_h(192x32)^T ----
        {
            f16x8 aof[3];
            #pragma unroll
            for (int a = 0; a < 3; ++a)
                aof[a] = *(const f16x8*)&AOh[(16 * (3 * mi + a) + l15) * QS + lg * 8];
            #pragma unroll
            for (int bq = 0; bq < 4; ++bq) {
                f16x8 bw = *(const f16x8*)&Wh[(16 * (4 * ni + bq) + l15) * QS + lg * 8];
                #pragma unroll
                for (int a = 0; a < 3; ++a)
                    pacc[a][bq] = __builtin_amdgcn_mfma_f32_16x16x32_f16(aof[a], bw, pacc[a][bq], 0, 0, 0);
            }
        }
        __syncthreads();   // D: protects Wh/Qh/Kh/Vt2/AOh rewrite next head

        if (h < 5 && tid < 512) { wpc[0] = wpn[0]; wpc[1] = wpn[1]; wpc[2] = wpn[2]; }
    }

    // ---- epilogue: pacc + bias -> out ----
    float bv[4];
    #pragma unroll
    for (int bq = 0; bq < 4; ++bq)
        bv[bq] = bproj[16 * (4 * ni + bq) + l15];
    #pragma unroll
    for (int a = 0; a < 3; ++a) {
        #pragma unroll
        for (int r = 0; r < 4; ++r) {
            int t = 16 * (3 * mi + a) + lg * 4 + r;
            int wi = t / 9, q = t - 9 * wi;
            long grow = rb0 + wi * 3 + (q / 3) * 288 + (q % 3);
            float* dst = out + grow * 192;
            #pragma unroll
            for (int bq = 0; bq < 4; ++bq)
                dst[16 * (4 * ni + bq) + l15] = pacc[a][bq][r] + bv[bq];
        }
    }
}

extern "C" void kernel_launch(void* const* d_in, const int* in_sizes, int n_in,
                              void* d_out, int out_size, void* d_ws, size_t ws_size,
                              hipStream_t stream) {
    const float* x     = (const float*)d_in[0];
    const float* Wqkv  = (const float*)d_in[1];
    const float* Wproj = (const float*)d_in[2];
    const float* bproj = (const float*)d_in[3];
    float* out = (float*)d_out;
    lsa_mfma2<<<1536, TPB, 0, stream>>>(x, Wqkv, Wproj, bproj, out);
}

// Round 4
// 241.760 us; speedup vs baseline: 3.1968x; 3.1968x over previous
//
#include <hip/hip_runtime.h>

typedef _Float16 f16;
typedef _Float16 f16x4 __attribute__((ext_vector_type(4)));
typedef _Float16 f16x8 __attribute__((ext_vector_type(8)));
typedef float f32x4 __attribute__((ext_vector_type(4)));

#define TPB 576            // 9 waves
#define NWIN 16            // windows per block
#define XS 200             // Xh row stride (halves): 400B = 25x16B
#define WSS 200            // Wh row stride
#define QS 40              // Qh/Kh/AOh/Wph row stride: 80B = 5x16B
#define VS 280             // Vt2 row stride: 560B = 35x16B
#define PS 40              // fallback P scratch row stride

#define HAVE_MFMA16 __has_builtin(__builtin_amdgcn_mfma_f32_16x16x16f16)

__global__ __launch_bounds__(TPB) void lsa_mfma3(
    const float* __restrict__ x, const float* __restrict__ Wqkv,
    const float* __restrict__ Wproj, const float* __restrict__ bproj,
    float* __restrict__ out)
{
    __shared__ f16 Xh[144 * XS];     // 57600 B
    __shared__ f16 Wh[96 * WSS];     // 38400 B (Wph aliases first 192*QS)
    __shared__ f16 Qh[151 * QS];     // 12080 B
    __shared__ f16 Kh[151 * QS];     // 12080 B
    __shared__ f16 Vt2[32 * VS];     // 17920 B
    __shared__ f16 AOh[144 * QS];    // 11520 B
#if !HAVE_MFMA16
    __shared__ f16 Ps[9 * 16 * PS];  // 11520 B (fallback only)
#endif

    const int tid  = threadIdx.x;
    const int lane = tid & 63;
    const int w    = tid >> 6;      // wave 0..8
    const int ci   = w / 3;         // channel-tile group (QKV) / M-group (proj)
    const int ti   = w % 3;         // token-tile group (QKV) / N-group (proj)
    const int l15  = lane & 15;
    const int lg   = lane >> 4;     // 0..3

    // ---- geometry: 16 windows per block ----
    const int  bb    = blockIdx.x / 768;
    const int  gbase = (blockIdx.x % 768) * NWIN;
    const long rb0   = (long)bb * 110592 + (long)(gbase / 96) * 864 + (long)(gbase % 96) * 3;

    // ---- phase 0: X -> LDS fp16; zero Vt2 (and Ps) ----
    for (int idx = tid; idx < 144 * 48; idx += TPB) {   // 12 exact iters
        int t = idx / 48, c4 = idx % 48;
        int wi = t / 9, q = t - 9 * wi;
        long grow = rb0 + wi * 3 + (q / 3) * 288 + (q % 3);
        float4 xv = ((const float4*)x)[grow * 48 + c4];
        union { f16 h[4]; ushort4 u; } tmp;
        tmp.h[0] = (f16)xv.x; tmp.h[1] = (f16)xv.y; tmp.h[2] = (f16)xv.z; tmp.h[3] = (f16)xv.w;
        *(ushort4*)&Xh[t * XS + c4 * 4] = tmp.u;
    }
    {
        int4 z = {0, 0, 0, 0};
        for (int i2 = tid; i2 < (32 * VS * 2) / 16; i2 += TPB) ((int4*)Vt2)[i2] = z;
#if !HAVE_MFMA16
        for (int i2 = tid; i2 < (9 * 16 * PS * 2) / 16; i2 += TPB) ((int4*)Ps)[i2] = z;
#endif
    }

    f32x4 pacc[3][4];
    #pragma unroll
    for (int a = 0; a < 3; ++a)
        #pragma unroll
        for (int bq = 0; bq < 4; ++bq)
            pacc[a][bq] = (f32x4){0.f, 0.f, 0.f, 0.f};

    __syncthreads();

    const float4* Wq4 = (const float4*)Wqkv;
    const float4* Wp4 = (const float4*)Wproj;

    for (int h = 0; h < 6; ++h) {
        // ---- stage Wqkv head slice: rows 0..31=Q, 32..63=K, 64..95=V ----
        #pragma unroll
        for (int i = 0; i < 8; ++i) {               // 8 exact iters
            int l = i * TPB + tid;
            int r = l / 48, c4 = l % 48;
            float4 wv = Wq4[((r >> 5) * 192 + h * 32 + (r & 31)) * 48 + c4];
            union { f16 h4[4]; ushort4 u; } t;
            t.h4[0] = (f16)wv.x; t.h4[1] = (f16)wv.y; t.h4[2] = (f16)wv.z; t.h4[3] = (f16)wv.w;
            *(ushort4*)&Wh[r * WSS + c4 * 4] = t.u;
        }
        __syncthreads();   // A: Wh ready

        // ---- QKV GEMM (swapped): A = W rows (channels), B = X rows (tokens) ----
        // D: row(4lg+r) = channel-in-tile, col(l15) = token-in-tile
        f32x4 qacc[2][3];
        #pragma unroll
        for (int c = 0; c < 2; ++c)
            #pragma unroll
            for (int t = 0; t < 3; ++t)
                qacc[c][t] = (f32x4){0.f, 0.f, 0.f, 0.f};
        #pragma unroll
        for (int kk = 0; kk < 6; ++kk) {
            f16x8 af[2], bf[3];
            #pragma unroll
            for (int c = 0; c < 2; ++c)
                af[c] = *(const f16x8*)&Wh[(16 * (ci + 3 * c) + l15) * WSS + kk * 32 + lg * 8];
            #pragma unroll
            for (int t = 0; t < 3; ++t)
                bf[t] = *(const f16x8*)&Xh[(16 * (ti + 3 * t) + l15) * XS + kk * 32 + lg * 8];
            #pragma unroll
            for (int c = 0; c < 2; ++c)
                #pragma unroll
                for (int t = 0; t < 3; ++t)
                    qacc[c][t] = __builtin_amdgcn_mfma_f32_16x16x32_f16(af[c], bf[t], qacc[c][t], 0, 0, 0);
        }
        // scatter: lane holds channels (ct*16 + 4lg .. +3) of token (16*tt + l15)
        #pragma unroll
        for (int c = 0; c < 2; ++c) {
            const int ct = ci + 3 * c;            // 0..5 wave-uniform
            #pragma unroll
            for (int t = 0; t < 3; ++t) {
                const int token = 16 * (ti + 3 * t) + l15;
                f16x4 ph;
                ph[0] = (f16)qacc[c][t][0]; ph[1] = (f16)qacc[c][t][1];
                ph[2] = (f16)qacc[c][t][2]; ph[3] = (f16)qacc[c][t][3];
                if (ct < 2) {
                    *(f16x4*)&Qh[token * QS + ct * 16 + 4 * lg] = ph;
                } else if (ct < 4) {
                    *(f16x4*)&Kh[token * QS + (ct - 2) * 16 + 4 * lg] = ph;
                } else {
                    const int d0 = (ct - 4) * 16 + 4 * lg;
                    int wi = token / 9, qq = token - 9 * wi;
                    #pragma unroll
                    for (int r = 0; r < 4; ++r)
                        Vt2[(d0 + r) * VS + 16 * wi + qq] = ph[r];
                }
            }
        }
        __syncthreads();   // B: Q/K/V ready; Wh reads done

        // ---- issue Wproj loads early (write LDS after attention) ----
        float4 wpv[3];
        if (tid < 512) {
            #pragma unroll
            for (int i = 0; i < 3; ++i) {
                int l = i * 512 + tid;
                int r = l / 8, c4 = l % 8;
                wpv[i] = Wp4[r * 48 + h * 8 + c4];
            }
        }

        // ---- attention: scores (A=K, B=Q) -> in-register softmax -> PV (A=V, B=P) ----
        for (int wi = w; wi < NWIN; wi += 9) {
            f16x8 ak = *(const f16x8*)&Kh[(9 * wi + l15) * QS + lg * 8];
            f16x8 aq = *(const f16x8*)&Qh[(9 * wi + l15) * QS + lg * 8];
            f32x4 s = (f32x4){0.f, 0.f, 0.f, 0.f};
            s = __builtin_amdgcn_mfma_f32_16x16x32_f16(ak, aq, s, 0, 0, 0);
            // lane holds S[k = 4lg+r][q = l15]
            float lgt[4];
            float mx = -1e30f;
            #pragma unroll
            for (int r = 0; r < 4; ++r) {
                int kx = 4 * lg + r;
                lgt[r] = (kx < 9) ? s[r] * 0.17677669529663687f : -1e30f;
                mx = fmaxf(mx, lgt[r]);
            }
            mx = fmaxf(mx, __shfl_xor(mx, 16));
            mx = fmaxf(mx, __shfl_xor(mx, 32));
            float e[4], sum = 0.f;
            #pragma unroll
            for (int r = 0; r < 4; ++r) {
                int kx = 4 * lg + r;
                e[r] = (kx < 9) ? __expf(lgt[r] - mx) : 0.f;
                sum += e[r];
            }
            sum += __shfl_xor(sum, 16);
            sum += __shfl_xor(sum, 32);
            float inv = 1.0f / sum;
            f16x4 p;
            p[0] = (f16)(e[0] * inv); p[1] = (f16)(e[1] * inv);
            p[2] = (f16)(e[2] * inv); p[3] = (f16)(e[3] * inv);
            // p IS the B-frag of 16x16x16: B[row=q=l15][k=4lg..+3]
#if HAVE_MFMA16
            #pragma unroll
            for (int dt = 0; dt < 2; ++dt) {
                f16x4 av = *(const f16x4*)&Vt2[(dt * 16 + l15) * VS + 16 * wi + 4 * lg];
                f32x4 o = (f32x4){0.f, 0.f, 0.f, 0.f};
                o = __builtin_amdgcn_mfma_f32_16x16x16f16(av, p, o, 0, 0, 0);
                // D: row(4lg+r) = d-in-tile, col(l15) = q
                if (l15 < 9) {
                    f16x4 oh;
                    oh[0] = (f16)o[0]; oh[1] = (f16)o[1]; oh[2] = (f16)o[2]; oh[3] = (f16)o[3];
                    *(f16x4*)&AOh[(9 * wi + l15) * QS + dt * 16 + 4 * lg] = oh;
                }
            }
#else
            {
                f16* myPs = &Ps[w * 16 * PS];
                #pragma unroll
                for (int r = 0; r < 4; ++r) myPs[l15 * PS + 4 * lg + r] = p[r];
                f16x8 pb = *(const f16x8*)&myPs[l15 * PS + 8 * lg];  // k 16..31 zero
                #pragma unroll
                for (int dt = 0; dt < 2; ++dt) {
                    f16x8 av8 = *(const f16x8*)&Vt2[(dt * 16 + l15) * VS + 16 * wi + 8 * lg];
                    f32x4 o = (f32x4){0.f, 0.f, 0.f, 0.f};
                    o = __builtin_amdgcn_mfma_f32_16x16x32_f16(av8, pb, o, 0, 0, 0);
                    if (l15 < 9) {
                        f16x4 oh;
                        oh[0] = (f16)o[0]; oh[1] = (f16)o[1]; oh[2] = (f16)o[2]; oh[3] = (f16)o[3];
                        *(f16x4*)&AOh[(9 * wi + l15) * QS + dt * 16 + 4 * lg] = oh;
                    }
                }
            }
#endif
        }

        // ---- write Wproj head slice into Wh alias (reads happen after barrier C) ----
        if (tid < 512) {
            #pragma unroll
            for (int i = 0; i < 3; ++i) {
                int l = i * 512 + tid;
                int r = l / 8, c4 = l % 8;
                union { f16 h4[4]; ushort4 u; } t;
                t.h4[0] = (f16)wpv[i].x; t.h4[1] = (f16)wpv[i].y;
                t.h4[2] = (f16)wpv[i].z; t.h4[3] = (f16)wpv[i].w;
                *(ushort4*)&Wh[r * QS + c4 * 4] = t.u;
            }
        }
        __syncthreads();   // C: AOh + Wph ready

        // ---- proj partial: out += AO_h(144x32) @ Wproj_h(192x32)^T ----
        {
            f16x8 aof[3];
            #pragma unroll
            for (int a = 0; a < 3; ++a)
                aof[a] = *(const f16x8*)&AOh[(16 * (3 * ci + a) + l15) * QS + lg * 8];
            #pragma unroll
            for (int bq = 0; bq < 4; ++bq) {
                f16x8 bw = *(const f16x8*)&Wh[(16 * (4 * ti + bq) + l15) * QS + lg * 8];
                #pragma unroll
                for (int a = 0; a < 3; ++a)
                    pacc[a][bq] = __builtin_amdgcn_mfma_f32_16x16x32_f16(aof[a], bw, pacc[a][bq], 0, 0, 0);
            }
        }
        __syncthreads();   // D: protects Wh/Qh/Kh/Vt2/AOh rewrite next head
    }

    // ---- epilogue: pacc + bias -> out (token = D row, channel = D col) ----
    float bv[4];
    #pragma unroll
    for (int bq = 0; bq < 4; ++bq)
        bv[bq] = bproj[16 * (4 * ti + bq) + l15];
    #pragma unroll
    for (int a = 0; a < 3; ++a) {
        #pragma unroll
        for (int r = 0; r < 4; ++r) {
            int t = 16 * (3 * ci + a) + lg * 4 + r;
            int wi = t / 9, q = t - 9 * wi;
            long grow = rb0 + wi * 3 + (q / 3) * 288 + (q % 3);
            float* dst = out + grow * 192;
            #pragma unroll
            for (int bq = 0; bq < 4; ++bq)
                dst[16 * (4 * ti + bq) + l15] = pacc[a][bq][r] + bv[bq];
        }
    }
}

extern "C" void kernel_launch(void* const* d_in, const int* in_sizes, int n_in,
                              void* d_out, int out_size, void* d_ws, size_t ws_size,
                              hipStream_t stream) {
    const float* x     = (const float*)d_in[0];
    const float* Wqkv  = (const float*)d_in[1];
    const float* Wproj = (const float*)d_in[2];
    const float* bproj = (const float*)d_in[3];
    float* out = (float*)d_out;
    lsa_mfma3<<<1536, TPB, 0, stream>>>(x, Wqkv, Wproj, bproj, out);
}